// Round 13
// baseline (97.113 us; speedup 1.0000x reference)
//
#include <hip/hip_runtime.h>

// Problem constants (fixed by setup_inputs / reference)
#define FH 2160
#define FW 3840
#define DH 1080
#define DW 1920
#define RAD 8
#define KS 17
#define INV_KS (1.0f / 17.0f)
#define EPS_GF 1e-3f
#define EPS_LOG 1e-6f
#define EPS_SCALE 1e-4f
#define A_COEF 0.7f

// K1 geometry: 32x32 core of D/a/b per block, D halo tile 48x48 built from x 96x96
#define TS 32
#define IT 48               // TS + 2*RAD
#define ITP 50              // EVEN padded stride (float2-aligned strip reads)
#define NT1 2040            // 60 x 34 tiles
#define TPX1 255            // tiles per XCD

// K2 geometry (wave-private): each wave owns 32w x 8h output px.
//   base tile 6r x 18c (4x16 core + bilinear +/-1), AB tile 22r x 34c.
// Block = 4 waves = 64w x 16h out px. Grid 60 x 135 = 8100 blocks.
#define W_ATR 22
#define W_ATC 34
#define W_HC 18
#define W_BR 6
#define W_BP 19
#define W_IN (W_ATR * W_ATC * 2)          // 1496 floats
#define W_HA (W_ATR * W_HC * 2)           // 792 floats
#define W_SZ 2404                         // 1496+792+114 padded (even, 16B-align ok)
#define NT2 8100

__device__ __forceinline__ int refl(int p, int n) {
    // jnp.pad 'reflect' (no edge repeat). Max overhang 17 << n, one fold suffices.
    p = (p < 0) ? -p : p;
    return (p >= n) ? (2 * n - 2 - p) : p;
}

__device__ __forceinline__ float luma3(float r, float g, float b) {
    return 0.2126f * r + 0.7152f * g + 0.0722f * b;
}

// ---- K1: x -> D, {a,b}  (downsample fused with GF stage 1) — unchanged (round 11) ----
__global__ void __launch_bounds__(256)
k_gf_front(const float* __restrict__ x, float* __restrict__ Dg,
           float2* __restrict__ ABg) {
    __shared__ float inD[IT * ITP];   // 48x50 = 9.6 KB
    __shared__ float2 hh[IT * TS];    // 48x32 f2 = 12.3 KB
    int bid = blockIdx.x;
    int swz = (bid & 7) * TPX1 + (bid >> 3);   // XCD-contiguous raster strips
    int bx = swz % 60, by = swz / 60;
    int tx0 = bx * TS, ty0 = by * TS;
    int t = threadIdx.x;

    for (int s = t; s < IT * IT; s += 256) {
        int li = s / IT, lj = s - li * IT;
        int gi = refl(ty0 - RAD + li, DH);
        int gj = refl(tx0 - RAD + lj, DW);
        const float* p0 = x + ((size_t)(2 * gi) * FW + (size_t)(2 * gj)) * 3;
        const float* p1 = p0 + (size_t)FW * 3;
        float2 a0 = *(const float2*)(p0);
        float2 a1 = *(const float2*)(p0 + 2);
        float2 a2 = *(const float2*)(p0 + 4);
        float2 b0 = *(const float2*)(p1);
        float2 b1 = *(const float2*)(p1 + 2);
        float2 b2 = *(const float2*)(p1 + 4);
        float y00 = fmaxf(luma3(a0.x, a0.y, a1.x), EPS_LOG);
        float y01 = fmaxf(luma3(a1.y, a2.x, a2.y), EPS_LOG);
        float y10 = fmaxf(luma3(b0.x, b0.y, b1.x), EPS_LOG);
        float y11 = fmaxf(luma3(b1.y, b2.x, b2.y), EPS_LOG);
        inD[li * ITP + lj] = 0.25f * __log2f((y00 * y01) * (y10 * y11));
    }
    __syncthreads();

    for (int task = t; task < IT * 8; task += 256) {
        int r = task >> 3, c0 = (task & 7) * 4;
        const float* row = &inD[r * ITP + c0];
        const float2* row2 = (const float2*)row;
        float s1 = 0.f, s2 = 0.f;
#pragma unroll
        for (int k = 0; k < 8; ++k) {
            float2 p = row2[k];
            s1 += p.x + p.y;
            s2 += p.x * p.x + p.y * p.y;
        }
        float v16 = row[16];
        s1 += v16; s2 += v16 * v16;
        int base = r * TS + c0;
        hh[base] = make_float2(s1 * INV_KS, s2 * INV_KS);
#pragma unroll
        for (int cc = 1; cc < 4; ++cc) {
            float vo = row[cc - 1], vi = row[cc + 16];
            s1 += vi - vo;
            s2 += vi * vi - vo * vo;
            hh[base + cc] = make_float2(s1 * INV_KS, s2 * INV_KS);
        }
    }
    __syncthreads();

    {
        int rs = t >> 5, c = t & 31;
        int r0 = rs * 4;
        float sx = 0.f, sy = 0.f;
#pragma unroll
        for (int k = 0; k < KS; ++k) {
            float2 h = hh[(r0 + k) * TS + c];
            sx += h.x; sy += h.y;
        }
#pragma unroll
        for (int rr = 0; rr < 4; ++rr) {
            int r = r0 + rr;
            if (rr > 0) {
                float2 hi = hh[(r + 16) * TS + c];
                float2 ho = hh[(r - 1) * TS + c];
                sx += hi.x - ho.x;
                sy += hi.y - ho.y;
            }
            int gi = ty0 + r;
            if (gi < DH) {
                float mI = sx * INV_KS, mII = sy * INV_KS;
                float var = mII - mI * mI;
                float av = var * __builtin_amdgcn_rcpf(var + EPS_GF);
                size_t g = (size_t)gi * DW + tx0 + c;
                ABg[g] = make_float2(av, mI - av * mI);
                Dg[g] = inD[(r + RAD) * ITP + c + RAD];
            }
        }
    }
}

// ---- K2: {a,b},D,x -> out — WAVE-PRIVATE, ZERO __syncthreads ----
__global__ void __launch_bounds__(256)
k_gf_back(const float* __restrict__ x, const float2* __restrict__ ABg,
          const float* __restrict__ Dg, float* __restrict__ out) {
    __shared__ float smem[4 * W_SZ];   // 38.5 KB -> 4 blocks/CU = 16 waves/CU
    int bid = blockIdx.x;
    // bijective XCD swizzle for 8100 blocks (8100 % 8 != 0)
    int xcd = bid & 7, o8 = bid >> 3;
    const int q = NT2 / 8, rm = NT2 % 8;   // 1012, 4
    int wg = (xcd < rm ? xcd * (q + 1) : rm * (q + 1) + (xcd - rm) * q) + o8;
    int bx = wg % 60, by = wg / 60;        // bx 0..59, by 0..134
    int t = threadIdx.x;
    int w = t >> 6, lane = t & 63;
    float* wls = smem + w * W_SZ;
    float2* inAB = (float2*)wls;
    float2* hAB = (float2*)(wls + W_IN);
    float* baseT = wls + W_IN + W_HA;

    int ox0 = bx * 64 + (w & 1) * 32;      // wave out origin (exact: 60*64=3840, 135*16=2160)
    int oy0 = by * 16 + (w >> 1) * 8;
    int bw0 = (ox0 >> 1) - 1, bh0 = (oy0 >> 1) - 1;
    int aw0 = bw0 - RAD, ah0 = bh0 - RAD;

    // P0: gather AB 22x34 (wave-private)
    if (ah0 >= 0 && ah0 + W_ATR <= DH && aw0 >= 0 && aw0 + W_ATC <= DW) {
        const float2* src = ABg + (size_t)ah0 * DW + aw0;
        for (int s = lane; s < W_ATR * W_ATC; s += 64) {
            int r = s / W_ATC, c = s - r * W_ATC;
            inAB[s] = src[(size_t)r * DW + c];
        }
    } else {
        for (int s = lane; s < W_ATR * W_ATC; s += 64) {
            int r = s / W_ATC, c = s - r * W_ATC;
            inAB[s] = ABg[(size_t)refl(ah0 + r, DH) * DW + refl(aw0 + c, DW)];
        }
    }
    asm volatile("s_waitcnt lgkmcnt(0)" ::: "memory");
    __builtin_amdgcn_sched_barrier(0);

    // P1: hbox 22 rows x 18 cols
    for (int s = lane; s < W_ATR * W_HC; s += 64) {
        int r = s / W_HC, c = s - r * W_HC;
        const float2* row = &inAB[r * W_ATC + c];
        float s1 = 0.f, s2 = 0.f;
#pragma unroll
        for (int k = 0; k < KS; ++k) { float2 v = row[k]; s1 += v.x; s2 += v.y; }
        hAB[s] = make_float2(s1 * INV_KS, s2 * INV_KS);
    }
    asm volatile("s_waitcnt lgkmcnt(0)" ::: "memory");
    __builtin_amdgcn_sched_barrier(0);

    // P2: vbox 6 rows x 18 cols -> base = mean_a * D + mean_b
    for (int s = lane; s < W_BR * W_HC; s += 64) {
        int r = s / W_HC, c = s - r * W_HC;
        float s1 = 0.f, s2 = 0.f;
#pragma unroll
        for (int k = 0; k < KS; ++k) {
            float2 v = hAB[(r + k) * W_HC + c];
            s1 += v.x; s2 += v.y;
        }
        size_t g = (size_t)refl(bh0 + r, DH) * DW + refl(bw0 + c, DW);
        baseT[r * W_BP + c] = (s1 * INV_KS) * Dg[g] + s2 * INV_KS;
    }
    asm volatile("s_waitcnt lgkmcnt(0)" ::: "memory");
    __builtin_amdgcn_sched_barrier(0);

    // P3: epilogue — exactly 1 quad of 4 px per lane (8 rows x 8 quads)
    {
        int qi = lane >> 3, qj = lane & 7;
        int oy = oy0 + qi;
        int ox0q = ox0 + qj * 4;
        size_t off = ((size_t)oy * FW + (size_t)ox0q) * 3;
        const float4* xin = (const float4*)(x + off);
        float4 v0 = xin[0], v1 = xin[1], v2 = xin[2];

        float ys = fminf(fmaxf((oy + 0.5f) * 0.5f - 0.5f, 0.f), (float)(DH - 1));
        int y0 = (int)ys;
        int y1 = min(y0 + 1, DH - 1);
        float wy = ys - (float)y0;
        const float* br0 = &baseT[(y0 - bh0) * W_BP];
        const float* br1 = &baseT[(y1 - bh0) * W_BP];

        float px[12] = {v0.x, v0.y, v0.z, v0.w, v1.x, v1.y, v1.z, v1.w,
                        v2.x, v2.y, v2.z, v2.w};
        float po[12];
#pragma unroll
        for (int p = 0; p < 4; ++p) {
            int ox = ox0q + p;
            float xs = fminf(fmaxf((ox + 0.5f) * 0.5f - 0.5f, 0.f), (float)(DW - 1));
            int x0 = (int)xs;
            int x1 = min(x0 + 1, DW - 1);
            float wx = xs - (float)x0;
            int c0 = x0 - bw0, c1 = x1 - bw0;
            float top = br0[c0] * (1.f - wx) + br0[c1] * wx;
            float bot = br1[c0] * (1.f - wx) + br1[c1] * wx;
            float Yb = top * (1.f - wy) + bot * wy;

            float cr = px[3 * p], cg = px[3 * p + 1], cb = px[3 * p + 2];
            float Y = luma3(cr, cg, cb);
            float Ylog = __log2f(fmaxf(Y, EPS_LOG));
            float Yout = exp2f(A_COEF * Yb + (Ylog - Yb));
            float sc = Yout * __builtin_amdgcn_rcpf(Y + EPS_SCALE);
            po[3 * p + 0] = fminf(fmaxf(cr * sc, 0.f), 1.f);
            po[3 * p + 1] = fminf(fmaxf(cg * sc, 0.f), 1.f);
            po[3 * p + 2] = fminf(fmaxf(cb * sc, 0.f), 1.f);
        }
        float4* op = (float4*)(out + off);
        op[0] = make_float4(po[0], po[1], po[2], po[3]);
        op[1] = make_float4(po[4], po[5], po[6], po[7]);
        op[2] = make_float4(po[8], po[9], po[10], po[11]);
    }
}

extern "C" void kernel_launch(void* const* d_in, const int* in_sizes, int n_in,
                              void* d_out, int out_size, void* d_ws, size_t ws_size,
                              hipStream_t stream) {
    const float* x = (const float*)d_in[0];
    float* out = (float*)d_out;
    float* ws = (float*)d_ws;
    const size_t DN = (size_t)DW * DH;  // 8.29 MB

    float* D = ws;                        // DN floats
    float2* AB = (float2*)(ws + DN);      // DN float2

    k_gf_front<<<dim3(NT1), dim3(256), 0, stream>>>(x, D, AB);
    k_gf_back <<<dim3(NT2), dim3(256), 0, stream>>>(x, AB, D, out);
}

// Round 14
// 74.472 us; speedup vs baseline: 1.3040x; 1.3040x over previous
//
#include <hip/hip_runtime.h>

// Problem constants (fixed by setup_inputs / reference)
#define FH 2160
#define FW 3840
#define DH 1080
#define DW 1920
#define RAD 8
#define KS 17
#define INV_KS (1.0f / 17.0f)
#define EPS_GF 1e-3f
#define EPS_LOG 1e-6f
#define EPS_SCALE 1e-4f
#define A_COEF 0.7f

// K1 geometry: 32x32 core of D/a/b per block, D halo tile 48x48 built from x 96x96
#define TS 32
#define IT 48               // TS + 2*RAD
#define ITP 50              // EVEN padded stride (float2-aligned strip reads)
#define NT1 2040            // 60 x 34 tiles
#define TPX1 255            // tiles per XCD

// K2 geometry: 64x32 output px per block; base tile 18x34 (16x32 core + bilinear +/-1);
// a/b footprint 34x50 (read straight from global, no LDS stage)
#define ATR 34              // AB rows
#define ATC 50              // AB cols
#define BTC 34              // base cols
#define BTR 18              // base rows
#define BTP 35
#define NT2 4080            // 60 x 68 tiles (% 8 == 0)
#define TPX2 510

__device__ __forceinline__ int refl(int p, int n) {
    // jnp.pad 'reflect' (no edge repeat). Max overhang 17 << n, one fold suffices.
    p = (p < 0) ? -p : p;
    return (p >= n) ? (2 * n - 2 - p) : p;
}

__device__ __forceinline__ float luma3(float r, float g, float b) {
    return 0.2126f * r + 0.7152f * g + 0.0722f * b;
}

// ---- K1: x -> D, {a,b}  (downsample fused with GF stage 1) — unchanged (round 11) ----
__global__ void __launch_bounds__(256)
k_gf_front(const float* __restrict__ x, float* __restrict__ Dg,
           float2* __restrict__ ABg) {
    __shared__ float inD[IT * ITP];   // 48x50 = 9.6 KB
    __shared__ float2 hh[IT * TS];    // 48x32 f2 = 12.3 KB
    int bid = blockIdx.x;
    int swz = (bid & 7) * TPX1 + (bid >> 3);   // XCD-contiguous raster strips
    int bx = swz % 60, by = swz / 60;
    int tx0 = bx * TS, ty0 = by * TS;
    int t = threadIdx.x;

    for (int s = t; s < IT * IT; s += 256) {
        int li = s / IT, lj = s - li * IT;
        int gi = refl(ty0 - RAD + li, DH);
        int gj = refl(tx0 - RAD + lj, DW);
        const float* p0 = x + ((size_t)(2 * gi) * FW + (size_t)(2 * gj)) * 3;
        const float* p1 = p0 + (size_t)FW * 3;
        float2 a0 = *(const float2*)(p0);
        float2 a1 = *(const float2*)(p0 + 2);
        float2 a2 = *(const float2*)(p0 + 4);
        float2 b0 = *(const float2*)(p1);
        float2 b1 = *(const float2*)(p1 + 2);
        float2 b2 = *(const float2*)(p1 + 4);
        float y00 = fmaxf(luma3(a0.x, a0.y, a1.x), EPS_LOG);
        float y01 = fmaxf(luma3(a1.y, a2.x, a2.y), EPS_LOG);
        float y10 = fmaxf(luma3(b0.x, b0.y, b1.x), EPS_LOG);
        float y11 = fmaxf(luma3(b1.y, b2.x, b2.y), EPS_LOG);
        inD[li * ITP + lj] = 0.25f * __log2f((y00 * y01) * (y10 * y11));
    }
    __syncthreads();

    for (int task = t; task < IT * 8; task += 256) {
        int r = task >> 3, c0 = (task & 7) * 4;
        const float* row = &inD[r * ITP + c0];
        const float2* row2 = (const float2*)row;
        float s1 = 0.f, s2 = 0.f;
#pragma unroll
        for (int k = 0; k < 8; ++k) {
            float2 p = row2[k];
            s1 += p.x + p.y;
            s2 += p.x * p.x + p.y * p.y;
        }
        float v16 = row[16];
        s1 += v16; s2 += v16 * v16;
        int base = r * TS + c0;
        hh[base] = make_float2(s1 * INV_KS, s2 * INV_KS);
#pragma unroll
        for (int cc = 1; cc < 4; ++cc) {
            float vo = row[cc - 1], vi = row[cc + 16];
            s1 += vi - vo;
            s2 += vi * vi - vo * vo;
            hh[base + cc] = make_float2(s1 * INV_KS, s2 * INV_KS);
        }
    }
    __syncthreads();

    {
        int rs = t >> 5, c = t & 31;
        int r0 = rs * 4;
        float sx = 0.f, sy = 0.f;
#pragma unroll
        for (int k = 0; k < KS; ++k) {
            float2 h = hh[(r0 + k) * TS + c];
            sx += h.x; sy += h.y;
        }
#pragma unroll
        for (int rr = 0; rr < 4; ++rr) {
            int r = r0 + rr;
            if (rr > 0) {
                float2 hi = hh[(r + 16) * TS + c];
                float2 ho = hh[(r - 1) * TS + c];
                sx += hi.x - ho.x;
                sy += hi.y - ho.y;
            }
            int gi = ty0 + r;
            if (gi < DH) {
                float mI = sx * INV_KS, mII = sy * INV_KS;
                float var = mII - mI * mI;
                float av = var * __builtin_amdgcn_rcpf(var + EPS_GF);
                size_t g = (size_t)gi * DW + tx0 + c;
                ABg[g] = make_float2(av, mI - av * mI);
                Dg[g] = inD[(r + RAD) * ITP + c + RAD];
            }
        }
    }
}

// ---- K2: {a,b},D,x -> out — hbox reads AB straight from global (no LDS stage) ----
// LDS 11.7 KB; phases: hbox -> vbox -> epilogue (2 barriers).
__global__ void __launch_bounds__(256)
k_gf_back(const float* __restrict__ x, const float2* __restrict__ ABg,
          const float* __restrict__ Dg, float* __restrict__ out) {
    __shared__ float2 hAB[ATR * BTC];     // 34x34 f2 = 9.2 KB
    __shared__ float baseT[BTR * BTP];    // 18x35 = 2.5 KB
    int bid = blockIdx.x;
    int swz = (bid & 7) * TPX2 + (bid >> 3);
    int bx = swz % 60, by = swz / 60;     // bx 0..59, by 0..67
    int ox0 = bx * 64, oy0 = by * 32;
    int bh0 = by * 16 - 1, bw0 = bx * 32 - 1;   // base tile origin (incl -1 bilinear halo)
    int ah0 = bh0 - RAD, aw0 = bw0 - RAD;       // a/b footprint origin
    int t = threadIdx.x;

    // Phase 0: hbox strip-4 direct from global. tasks = 34 rows x 9 strips = 306.
    bool int_c = (aw0 >= 0 && aw0 + ATC <= DW);
    for (int task = t; task < ATR * 9; task += 256) {
        int r = task / 9, c0 = (task - r * 9) * 4;
        const float2* rowp = ABg + (size_t)refl(ah0 + r, DH) * DW;
        int base = r * BTC + c0;
        if (int_c) {
            const float2* p = rowp + (aw0 + c0);
            float s1 = 0.f, s2 = 0.f;
#pragma unroll
            for (int k = 0; k < KS; ++k) { float2 v = p[k]; s1 += v.x; s2 += v.y; }
#pragma unroll
            for (int cc = 0; cc < 4; ++cc) {
                if (cc > 0) {
                    float2 vi = p[cc + 16], vo = p[cc - 1];
                    s1 += vi.x - vo.x;
                    s2 += vi.y - vo.y;
                }
                if (c0 + cc < BTC) hAB[base + cc] = make_float2(s1 * INV_KS, s2 * INV_KS);
            }
        } else {
            // edge path: full 17-tap per col with per-tap column refl (no slide)
#pragma unroll
            for (int cc = 0; cc < 4; ++cc) {
                if (c0 + cc < BTC) {
                    float s1 = 0.f, s2 = 0.f;
#pragma unroll
                    for (int k = 0; k < KS; ++k) {
                        float2 v = rowp[refl(aw0 + c0 + cc + k, DW)];
                        s1 += v.x; s2 += v.y;
                    }
                    hAB[base + cc] = make_float2(s1 * INV_KS, s2 * INV_KS);
                }
            }
        }
    }
    __syncthreads();

    // Phase 1: vbox, 5 row-strips of sizes {4,4,4,4,2}. tasks = 5 x 34 = 170.
    for (int task = t; task < 5 * BTC; task += 256) {
        int rs = task / BTC, c = task - rs * BTC;
        int r0 = rs * 4;
        int sz = (rs == 4) ? 2 : 4;
        float s1 = 0.f, s2 = 0.f;
#pragma unroll
        for (int k = 0; k < KS; ++k) {
            float2 v = hAB[(r0 + k) * BTC + c];
            s1 += v.x; s2 += v.y;
        }
        for (int rr = 0; rr < sz; ++rr) {
            int r = r0 + rr;
            if (rr > 0) {
                float2 vi = hAB[(r + 16) * BTC + c];
                float2 vo = hAB[(r - 1) * BTC + c];
                s1 += vi.x - vo.x;
                s2 += vi.y - vo.y;
            }
            size_t g = (size_t)refl(bh0 + r, DH) * DW + refl(bw0 + c, DW);
            baseT[r * BTP + c] = (s1 * INV_KS) * Dg[g] + s2 * INV_KS;
        }
    }
    __syncthreads();

    // Phase 2: upsample base from LDS + tonemap + scale + clip; 32 rows x 16 quads
    for (int q = t; q < 32 * 16; q += 256) {
        int qi = q >> 4, qj = q & 15;
        int oy = oy0 + qi;
        if (oy < FH) {
            float ys = fminf(fmaxf((oy + 0.5f) * 0.5f - 0.5f, 0.f), (float)(DH - 1));
            int y0 = (int)ys;
            int y1 = min(y0 + 1, DH - 1);
            float wy = ys - (float)y0;
            const float* br0 = &baseT[(y0 - bh0) * BTP];
            const float* br1 = &baseT[(y1 - bh0) * BTP];

            size_t off = ((size_t)oy * FW + (size_t)(ox0 + 4 * qj)) * 3;
            const float4* xin = (const float4*)(x + off);
            float4 v0 = xin[0], v1 = xin[1], v2 = xin[2];
            float px[12] = {v0.x, v0.y, v0.z, v0.w, v1.x, v1.y, v1.z, v1.w,
                            v2.x, v2.y, v2.z, v2.w};
            float po[12];
#pragma unroll
            for (int p = 0; p < 4; ++p) {
                int ox = ox0 + 4 * qj + p;
                float xs = fminf(fmaxf((ox + 0.5f) * 0.5f - 0.5f, 0.f), (float)(DW - 1));
                int x0 = (int)xs;
                int x1 = min(x0 + 1, DW - 1);
                float wx = xs - (float)x0;
                int c0 = x0 - bw0, c1 = x1 - bw0;
                float top = br0[c0] * (1.f - wx) + br0[c1] * wx;
                float bot = br1[c0] * (1.f - wx) + br1[c1] * wx;
                float Yb = top * (1.f - wy) + bot * wy;

                float cr = px[3 * p], cg = px[3 * p + 1], cb = px[3 * p + 2];
                float Y = luma3(cr, cg, cb);
                float Ylog = __log2f(fmaxf(Y, EPS_LOG));
                float Yout = exp2f(A_COEF * Yb + (Ylog - Yb));
                float sc = Yout * __builtin_amdgcn_rcpf(Y + EPS_SCALE);
                po[3 * p + 0] = fminf(fmaxf(cr * sc, 0.f), 1.f);
                po[3 * p + 1] = fminf(fmaxf(cg * sc, 0.f), 1.f);
                po[3 * p + 2] = fminf(fmaxf(cb * sc, 0.f), 1.f);
            }
            float4* op = (float4*)(out + off);
            op[0] = make_float4(po[0], po[1], po[2], po[3]);
            op[1] = make_float4(po[4], po[5], po[6], po[7]);
            op[2] = make_float4(po[8], po[9], po[10], po[11]);
        }
    }
}

extern "C" void kernel_launch(void* const* d_in, const int* in_sizes, int n_in,
                              void* d_out, int out_size, void* d_ws, size_t ws_size,
                              hipStream_t stream) {
    const float* x = (const float*)d_in[0];
    float* out = (float*)d_out;
    float* ws = (float*)d_ws;
    const size_t DN = (size_t)DW * DH;  // 8.29 MB

    float* D = ws;                        // DN floats
    float2* AB = (float2*)(ws + DN);      // DN float2

    k_gf_front<<<dim3(NT1), dim3(256), 0, stream>>>(x, D, AB);
    k_gf_back <<<dim3(NT2), dim3(256), 0, stream>>>(x, AB, D, out);
}

// Round 15
// 71.412 us; speedup vs baseline: 1.3599x; 1.0429x over previous
//
#include <hip/hip_runtime.h>

// Problem constants (fixed by setup_inputs / reference)
#define FH 2160
#define FW 3840
#define DH 1080
#define DW 1920
#define RAD 8
#define KS 17
#define INV_KS (1.0f / 17.0f)
#define EPS_GF 1e-3f
#define EPS_LOG 1e-6f
#define EPS_SCALE 1e-4f
#define A_COEF 0.7f

// K1 geometry: 32x32 core of D/a/b per block, D halo tile 48x48 built from x 96x96
#define TS 32
#define IT 48               // TS + 2*RAD
#define ITP 50              // EVEN padded stride (float2-aligned strip reads)
#define NT1 2040            // 60 x 34 tiles
#define TPX1 255            // tiles per XCD

// K2 geometry: 64x32 output px per block; base tile 18x34 (16x32 core + bilinear +/-1);
// a/b tile 34x50
#define ATR 34              // AB rows
#define ATC 50              // AB cols
#define ATP2 52             // even float2 stride, cols 50/51 = tail padding
#define BTC 34              // base cols
#define BTR 18              // base rows
#define BTP 35
#define NT2 4080            // 60 x 68 tiles (% 8 == 0)
#define TPX2 510

__device__ __forceinline__ int refl(int p, int n) {
    // jnp.pad 'reflect' (no edge repeat). Max overhang 17 << n, one fold suffices.
    p = (p < 0) ? -p : p;
    return (p >= n) ? (2 * n - 2 - p) : p;
}

__device__ __forceinline__ float luma3(float r, float g, float b) {
    return 0.2126f * r + 0.7152f * g + 0.0722f * b;
}

// ---- K1: x -> D, {a,b}  (downsample fused with GF stage 1) ----
__global__ void __launch_bounds__(256)
k_gf_front(const float* __restrict__ x, float* __restrict__ Dg,
           float2* __restrict__ ABg) {
    __shared__ float inD[IT * ITP];   // 48x50 = 9.6 KB
    __shared__ float2 hh[IT * TS];    // 48x32 f2 = 12.3 KB  (.x = I taps, .y = I*I taps)
    int bid = blockIdx.x;
    int swz = (bid & 7) * TPX1 + (bid >> 3);   // XCD-contiguous raster strips
    int bx = swz % 60, by = swz / 60;
    int tx0 = bx * TS, ty0 = by * TS;
    int t = threadIdx.x;

    // Phase 1: D halo tile from x (luma -> log2 -> 2x2 mean).
    // DOWN=0.5 align_corners=False bilinear == exact 2x2 mean; sum of 4 log2 == log2 of product.
    for (int s = t; s < IT * IT; s += 256) {
        int li = s / IT, lj = s - li * IT;
        int gi = refl(ty0 - RAD + li, DH);
        int gj = refl(tx0 - RAD + lj, DW);
        const float* p0 = x + ((size_t)(2 * gi) * FW + (size_t)(2 * gj)) * 3;
        const float* p1 = p0 + (size_t)FW * 3;
        float2 a0 = *(const float2*)(p0);
        float2 a1 = *(const float2*)(p0 + 2);
        float2 a2 = *(const float2*)(p0 + 4);
        float2 b0 = *(const float2*)(p1);
        float2 b1 = *(const float2*)(p1 + 2);
        float2 b2 = *(const float2*)(p1 + 4);
        float y00 = fmaxf(luma3(a0.x, a0.y, a1.x), EPS_LOG);
        float y01 = fmaxf(luma3(a1.y, a2.x, a2.y), EPS_LOG);
        float y10 = fmaxf(luma3(b0.x, b0.y, b1.x), EPS_LOG);
        float y11 = fmaxf(luma3(b1.y, b2.x, b2.y), EPS_LOG);
        inD[li * ITP + lj] = 0.25f * __log2f((y00 * y01) * (y10 * y11));
    }
    __syncthreads();

    // Phase 2: hbox of I and I*I, strip-4 sliding. tasks = 48 rows x 8 strips = 384
    for (int task = t; task < IT * 8; task += 256) {
        int r = task >> 3, c0 = (task & 7) * 4;
        const float* row = &inD[r * ITP + c0];
        const float2* row2 = (const float2*)row;   // (r*50 + c0) even -> 8B aligned
        float s1 = 0.f, s2 = 0.f;
#pragma unroll
        for (int k = 0; k < 8; ++k) {
            float2 p = row2[k];
            s1 += p.x + p.y;
            s2 += p.x * p.x + p.y * p.y;
        }
        float v16 = row[16];
        s1 += v16; s2 += v16 * v16;
        int base = r * TS + c0;
        hh[base] = make_float2(s1 * INV_KS, s2 * INV_KS);
#pragma unroll
        for (int cc = 1; cc < 4; ++cc) {
            float vo = row[cc - 1], vi = row[cc + 16];
            s1 += vi - vo;
            s2 += vi * vi - vo * vo;
            hh[base + cc] = make_float2(s1 * INV_KS, s2 * INV_KS);
        }
    }
    __syncthreads();

    // Phase 3: vbox strip-4 -> a,b ; also write D core. tasks = 8 rstrips x 32 cols = 256
    {
        int rs = t >> 5, c = t & 31;
        int r0 = rs * 4;
        float sx = 0.f, sy = 0.f;
#pragma unroll
        for (int k = 0; k < KS; ++k) {
            float2 h = hh[(r0 + k) * TS + c];
            sx += h.x; sy += h.y;
        }
#pragma unroll
        for (int rr = 0; rr < 4; ++rr) {
            int r = r0 + rr;
            if (rr > 0) {
                float2 hi = hh[(r + 16) * TS + c];
                float2 ho = hh[(r - 1) * TS + c];
                sx += hi.x - ho.x;
                sy += hi.y - ho.y;
            }
            int gi = ty0 + r;
            if (gi < DH) {
                float mI = sx * INV_KS, mII = sy * INV_KS;
                float var = mII - mI * mI;
                float av = var * __builtin_amdgcn_rcpf(var + EPS_GF);
                size_t g = (size_t)gi * DW + tx0 + c;
                ABg[g] = make_float2(av, mI - av * mI);
                Dg[g] = inD[(r + RAD) * ITP + c + RAD];
            }
        }
    }
}

// ---- K2: {a,b},D,x -> out  (GF stage 2 fused with upsample + tonemap) ----
// 64x32 output px per block; LDS 25.9 KB -> 6 blocks/CU.
__global__ void __launch_bounds__(256)
k_gf_back(const float* __restrict__ x, const float2* __restrict__ ABg,
          const float* __restrict__ Dg, float* __restrict__ out) {
    __shared__ float2 inAB[ATR * ATP2];   // 34x52 f2 = 14.1 KB (cols 50/51 pad)
    __shared__ float2 hAB[ATR * BTC];     // 34x34 f2 = 9.2 KB
    __shared__ float baseT[BTR * BTP];    // 18x35 = 2.5 KB
    int bid = blockIdx.x;
    int swz = (bid & 7) * TPX2 + (bid >> 3);
    int bx = swz % 60, by = swz / 60;     // bx 0..59, by 0..67
    int ox0 = bx * 64, oy0 = by * 32;
    int bh0 = by * 16 - 1, bw0 = bx * 32 - 1;   // base tile origin (incl -1 bilinear halo)
    int ah0 = bh0 - RAD, aw0 = bw0 - RAD;       // a/b tile origin
    int t = threadIdx.x;

    // Phase 0: gather AB tile 34x50; interior fast path (~92% of blocks) skips refl
    if (ah0 >= 0 && ah0 + ATR <= DH && aw0 >= 0 && aw0 + ATC <= DW) {
        const float2* src = ABg + (size_t)ah0 * DW + aw0;
        for (int s = t; s < ATR * ATC; s += 256) {
            int li = s / ATC, lj = s - li * ATC;
            inAB[li * ATP2 + lj] = src[(size_t)li * DW + lj];
        }
    } else {
        for (int s = t; s < ATR * ATC; s += 256) {
            int li = s / ATC, lj = s - li * ATC;
            inAB[li * ATP2 + lj] = ABg[(size_t)refl(ah0 + li, DH) * DW + refl(aw0 + lj, DW)];
        }
    }
    __syncthreads();

    // Phase 1: hbox strip-4. tasks = 34 rows x 9 strips = 306. Tail strip (c0=32)
    // slides into in-row padding (stale) AFTER its last in-range write -> harmless.
    for (int task = t; task < ATR * 9; task += 256) {
        int r = task / 9, c0 = (task - r * 9) * 4;
        const float2* row = &inAB[r * ATP2 + c0];
        float s1 = 0.f, s2 = 0.f;
#pragma unroll
        for (int k = 0; k < KS; ++k) { float2 v = row[k]; s1 += v.x; s2 += v.y; }
        int base = r * BTC + c0;
#pragma unroll
        for (int cc = 0; cc < 4; ++cc) {
            if (cc > 0) {
                float2 vi = row[cc + 16], vo = row[cc - 1];
                s1 += vi.x - vo.x;
                s2 += vi.y - vo.y;
            }
            if (c0 + cc < BTC) hAB[base + cc] = make_float2(s1 * INV_KS, s2 * INV_KS);
        }
    }
    __syncthreads();

    // Phase 2: vbox, 5 row-strips of sizes {4,4,4,4,2}. tasks = 5 x 34 = 170.
    for (int task = t; task < 5 * BTC; task += 256) {
        int rs = task / BTC, c = task - rs * BTC;
        int r0 = rs * 4;
        int sz = (rs == 4) ? 2 : 4;
        float s1 = 0.f, s2 = 0.f;
#pragma unroll
        for (int k = 0; k < KS; ++k) {
            float2 v = hAB[(r0 + k) * BTC + c];
            s1 += v.x; s2 += v.y;
        }
        for (int rr = 0; rr < sz; ++rr) {
            int r = r0 + rr;
            if (rr > 0) {
                float2 vi = hAB[(r + 16) * BTC + c];
                float2 vo = hAB[(r - 1) * BTC + c];
                s1 += vi.x - vo.x;
                s2 += vi.y - vo.y;
            }
            size_t g = (size_t)refl(bh0 + r, DH) * DW + refl(bw0 + c, DW);
            baseT[r * BTP + c] = (s1 * INV_KS) * Dg[g] + s2 * INV_KS;
        }
    }
    __syncthreads();

    // Phase 3: upsample base from LDS + tonemap + scale + clip; 32 rows x 16 quads
    for (int q = t; q < 32 * 16; q += 256) {
        int qi = q >> 4, qj = q & 15;
        int oy = oy0 + qi;
        if (oy < FH) {
            float ys = fminf(fmaxf((oy + 0.5f) * 0.5f - 0.5f, 0.f), (float)(DH - 1));
            int y0 = (int)ys;
            int y1 = min(y0 + 1, DH - 1);
            float wy = ys - (float)y0;
            const float* br0 = &baseT[(y0 - bh0) * BTP];
            const float* br1 = &baseT[(y1 - bh0) * BTP];

            size_t off = ((size_t)oy * FW + (size_t)(ox0 + 4 * qj)) * 3;
            const float4* xin = (const float4*)(x + off);
            float4 v0 = xin[0], v1 = xin[1], v2 = xin[2];
            float px[12] = {v0.x, v0.y, v0.z, v0.w, v1.x, v1.y, v1.z, v1.w,
                            v2.x, v2.y, v2.z, v2.w};
            float po[12];
#pragma unroll
            for (int p = 0; p < 4; ++p) {
                int ox = ox0 + 4 * qj + p;
                float xs = fminf(fmaxf((ox + 0.5f) * 0.5f - 0.5f, 0.f), (float)(DW - 1));
                int x0 = (int)xs;
                int x1 = min(x0 + 1, DW - 1);
                float wx = xs - (float)x0;
                int c0 = x0 - bw0, c1 = x1 - bw0;
                float top = br0[c0] * (1.f - wx) + br0[c1] * wx;
                float bot = br1[c0] * (1.f - wx) + br1[c1] * wx;
                float Yb = top * (1.f - wy) + bot * wy;

                float cr = px[3 * p], cg = px[3 * p + 1], cb = px[3 * p + 2];
                float Y = luma3(cr, cg, cb);
                float Ylog = __log2f(fmaxf(Y, EPS_LOG));
                float Yout = exp2f(A_COEF * Yb + (Ylog - Yb));
                float sc = Yout * __builtin_amdgcn_rcpf(Y + EPS_SCALE);
                po[3 * p + 0] = fminf(fmaxf(cr * sc, 0.f), 1.f);
                po[3 * p + 1] = fminf(fmaxf(cg * sc, 0.f), 1.f);
                po[3 * p + 2] = fminf(fmaxf(cb * sc, 0.f), 1.f);
            }
            float4* op = (float4*)(out + off);
            op[0] = make_float4(po[0], po[1], po[2], po[3]);
            op[1] = make_float4(po[4], po[5], po[6], po[7]);
            op[2] = make_float4(po[8], po[9], po[10], po[11]);
        }
    }
}

extern "C" void kernel_launch(void* const* d_in, const int* in_sizes, int n_in,
                              void* d_out, int out_size, void* d_ws, size_t ws_size,
                              hipStream_t stream) {
    const float* x = (const float*)d_in[0];
    float* out = (float*)d_out;
    float* ws = (float*)d_ws;
    const size_t DN = (size_t)DW * DH;  // 8.29 MB

    float* D = ws;                        // DN floats
    float2* AB = (float2*)(ws + DN);      // DN float2

    k_gf_front<<<dim3(NT1), dim3(256), 0, stream>>>(x, D, AB);
    k_gf_back <<<dim3(NT2), dim3(256), 0, stream>>>(x, AB, D, out);
}